// Round 13
// baseline (139.865 us; speedup 1.0000x reference)
//
#include <hip/hip_runtime.h>

#define B_ 16
#define S_ 2048
#define D_ 128

typedef __attribute__((ext_vector_type(8))) short bf16x8;
typedef __attribute__((ext_vector_type(4))) float f32x4;
typedef __attribute__((ext_vector_type(16))) float f32x16;
typedef __attribute__((ext_vector_type(2))) unsigned int u32x2;
typedef __attribute__((ext_vector_type(4))) unsigned int u32x4;

__device__ __forceinline__ unsigned short f2bf(float f) {
    unsigned int u = __builtin_bit_cast(unsigned int, f);
    u += 0x7fff + ((u >> 16) & 1);   // RNE
    return (unsigned short)(u >> 16);
}

__device__ __forceinline__ void gload16(const void* g, void* l) {
    __builtin_amdgcn_global_load_lds(
        (const __attribute__((address_space(1))) void*)g,
        (__attribute__((address_space(3))) void*)l, 16, 0, 0);
}

#define WAITV(n) asm volatile("s_waitcnt vmcnt(" #n ")" ::: "memory")

// T1: XCD-aware bijective swizzle (512 blocks, 8 XCDs -> XCD x owns batches {2x,2x+1}
//     -> per-XCD K/V working set 4MB = L2 fit)
__device__ __forceinline__ int xcd_swz(int raw) { return (raw & 7) * 64 + (raw >> 3); }

// ============ kernel 1: convert K & V -> bf16 swizzled tiles ============
// K tile (b*32+kt): row r, 16B chunk j at byte r*256 + ((j ^ (r&7))<<4)
// V tile: TRANSPOSED [d][kcol]: row d, chunk jc at byte d*128 + ((jc ^ (d&7))<<4)
__global__ __launch_bounds__(256, 4)
void conv_kv(const float* __restrict__ kg, const float* __restrict__ vg,
             char* __restrict__ kws, char* __restrict__ vws)
{
    __shared__ float lt[64 * 132];
    const int raw = blockIdx.x;
    const int tid = threadIdx.x;
    if (raw < 512) {                                // ---- K path ----
        const int bid = xcd_swz(raw);
        const float* src = kg + ((long)bid << 13);
        char* dst = kws + ((long)bid << 14);
#pragma unroll
        for (int it = 0; it < 4; ++it) {
            const int c = tid + it * 256;
            const int r = c >> 4, j = c & 15;
            f32x4 a = *(const f32x4*)(src + r * 128 + j * 8);
            f32x4 cc = *(const f32x4*)(src + r * 128 + j * 8 + 4);
            u32x4 p;
            p[0] = (unsigned)f2bf(a[0]) | ((unsigned)f2bf(a[1]) << 16);
            p[1] = (unsigned)f2bf(a[2]) | ((unsigned)f2bf(a[3]) << 16);
            p[2] = (unsigned)f2bf(cc[0]) | ((unsigned)f2bf(cc[1]) << 16);
            p[3] = (unsigned)f2bf(cc[2]) | ((unsigned)f2bf(cc[3]) << 16);
            *(u32x4*)(dst + r * 256 + ((j ^ (r & 7)) << 4)) = p;
        }
    } else {                                        // ---- V path (transposed) ----
        const int vb = xcd_swz(raw - 512);
        const float* src = vg + ((long)vb << 13);
        char* dst = vws + ((long)vb << 14);
#pragma unroll
        for (int it = 0; it < 8; ++it) {
            const int c = tid + it * 256;
            const int r = c >> 5, q = c & 31;
            *(f32x4*)(lt + r * 132 + q * 4) = *(const f32x4*)(src + r * 128 + q * 4);
        }
        __syncthreads();
#pragma unroll
        for (int it = 0; it < 4; ++it) {
            const int c = tid + it * 256;
            const int d = c >> 3, jc = c & 7;
            unsigned short e[8];
#pragma unroll
            for (int ee = 0; ee < 8; ++ee) e[ee] = f2bf(lt[(jc * 8 + ee) * 132 + d]);
            u32x4 p;
            p[0] = (unsigned)e[0] | ((unsigned)e[1] << 16);
            p[1] = (unsigned)e[2] | ((unsigned)e[3] << 16);
            p[2] = (unsigned)e[4] | ((unsigned)e[5] << 16);
            p[3] = (unsigned)e[6] | ((unsigned)e[7] << 16);
            *(u32x4*)(dst + d * 128 + ((jc ^ (d & 7)) << 4)) = p;
        }
    }
}

// balanced q-tile map: co-resident raw i,i+256 -> logical (b,t),(b+1,t); flip on b&1
__device__ __forceinline__ int qtile_of(int b, int t) {
    const int f = (t & 1) ? (t >> 1) : (31 - (t >> 1));
    return (b & 1) ? (31 - f) : f;
}

// ============ kernel 2: SINGLE-PASS flash — QK once, unnorm P->attn, sum, PV,
//              then in-place normalize of own region + zero-fill ============
__global__ __launch_bounds__(256, 2)
void flash_single(const float* __restrict__ qg, const char* __restrict__ kws,
                  const char* __restrict__ vws,
                  float* __restrict__ outg, float* __restrict__ attng)
{
    __shared__ char lds[65536];   // K dbuf @0/16384, V dbuf @32768/49152
                                  // epilogue: sums @0, invl64 @512, red @8192

    const int tid = threadIdx.x, lane = tid & 63, w = tid >> 6;
    const int wq = w >> 1, wk = w & 1;
    const int l31 = lane & 31, hi = lane >> 5;
    const int bid = xcd_swz(blockIdx.x);
    const int b = bid >> 5;
    const int qt = qtile_of(b, bid & 31);
    const int q0 = qt * 64;
    const int nt = qt + 1;
    const float scale = 0.088388347648318447f;
    const int qrow = q0 + wq * 32 + l31;

    bf16x8 qf[8];
    {
        const float* qr = qg + ((long)b * S_ + qrow) * D_;
#pragma unroll
        for (int km = 0; km < 8; ++km) {
            const int d0 = km * 16 + hi * 8;
            f32x4 a = *(const f32x4*)(qr + d0);
            f32x4 c = *(const f32x4*)(qr + d0 + 4);
            bf16x8 t;
            t[0] = (short)f2bf(a[0]); t[1] = (short)f2bf(a[1]);
            t[2] = (short)f2bf(a[2]); t[3] = (short)f2bf(a[3]);
            t[4] = (short)f2bf(c[0]); t[5] = (short)f2bf(c[1]);
            t[6] = (short)f2bf(c[2]); t[7] = (short)f2bf(c[3]);
            qf[km] = t;
        }
    }
    WAITV(0);   // drain q loads so counted vmcnt is exact

    const char* kb0 = kws + ((long)(b * 32) << 14);
    const char* vb0 = vws + ((long)(b * 32) << 14);
    const int krow = wk * 32 + l31;
    const int krb = krow * 256;
    const int ksw = krow & 7;

    f32x16 oacc[4];
#pragma unroll
    for (int dt = 0; dt < 4; ++dt)
#pragma unroll
        for (int i = 0; i < 16; ++i) oacc[dt][i] = 0.f;
    float sumA = 0.f;

    float* attn_row = attng + ((long)b * S_ + qrow) * S_;

#pragma unroll
    for (int it = 0; it < 4; ++it)
        gload16(kb0 + it * 4096 + tid * 16, lds + it * 4096 + tid * 16);
#pragma unroll
    for (int it = 0; it < 4; ++it)
        gload16(vb0 + it * 4096 + tid * 16, lds + 32768 + it * 4096 + tid * 16);

    int buf = 0;
    for (int kt = 0; kt < nt; ++kt) {
        const bool pf = (kt + 1 < nt);
        if (pf) {
            const char* kn = kb0 + ((long)(kt + 1) << 14);
            const char* vn = vb0 + ((long)(kt + 1) << 14);
            const int db = (buf ^ 1) * 16384;
#pragma unroll
            for (int it = 0; it < 4; ++it)
                gload16(kn + it * 4096 + tid * 16, lds + db + it * 4096 + tid * 16);
#pragma unroll
            for (int it = 0; it < 4; ++it)
                gload16(vn + it * 4096 + tid * 16, lds + 32768 + db + it * 4096 + tid * 16);
        }
        // per-wave FIFO: retire this tile's 8 loads; newer = (pf?8:0) loads + (kt?4:0) stores
        if (kt == 0) { if (pf) { WAITV(8); } else { WAITV(0); } }
        else         { if (pf) { WAITV(12); } else { WAITV(4); } }
        __builtin_amdgcn_s_barrier();
        __builtin_amdgcn_sched_barrier(0);

        const char* kbuf = lds + buf * 16384;
        const char* vbuf = lds + 32768 + buf * 16384;

        f32x16 a0, a1;
#pragma unroll
        for (int i = 0; i < 16; ++i) { a0[i] = 0.f; a1[i] = 0.f; }
        __builtin_amdgcn_s_setprio(1);
#pragma unroll
        for (int km = 0; km < 8; ++km) {
            bf16x8 kf = *(const bf16x8*)(kbuf + krb + (((km * 2 + hi) ^ ksw) << 4));
            if (km & 1) a1 = __builtin_amdgcn_mfma_f32_32x32x16_bf16(kf, qf[km], a1, 0, 0, 0);
            else        a0 = __builtin_amdgcn_mfma_f32_32x32x16_bf16(kf, qf[km], a0, 0, 0, 0);
        }
        __builtin_amdgcn_s_setprio(0);

        // softmax numerators (unnormalized) + row-sum + bf16 pack
        const int kbase = kt * 64 + wk * 32;
        unsigned W[8], PW[8];
#pragma unroll
        for (int i = 0; i < 8; ++i) {
            const int r0 = 2 * i;
            const int kl0 = (r0 & 3) + 8 * (r0 >> 2) + 4 * hi;
            const float p0 = (kbase + kl0 > qrow) ? 0.f : __expf((a0[r0] + a1[r0]) * scale);
            const float p1 = (kbase + kl0 + 1 > qrow) ? 0.f : __expf((a0[r0 + 1] + a1[r0 + 1]) * scale);
            sumA += p0 + p1;
            W[i] = (unsigned)f2bf(p0) | ((unsigned)f2bf(p1) << 16);
        }
#pragma unroll
        for (int i = 0; i < 8; ++i)
            PW[i] = (unsigned)__shfl_xor((int)W[i], 32, 64);

        // PV A-frags
        bf16x8 pa[2];
        u32x4 frs[2];
#pragma unroll
        for (int kc = 0; kc < 2; ++kc) {
            u32x4 fr;
            fr[0] = hi ? PW[kc * 4 + 2] : W[kc * 4 + 0];
            fr[1] = hi ? PW[kc * 4 + 3] : W[kc * 4 + 1];
            fr[2] = hi ? W[kc * 4 + 2] : PW[kc * 4 + 0];
            fr[3] = hi ? W[kc * 4 + 3] : PW[kc * 4 + 1];
            frs[kc] = fr;
            pa[kc] = __builtin_bit_cast(bf16x8, fr);
        }

        // PV first (matrix pipe), attn stores issue under it
        __builtin_amdgcn_s_setprio(1);
#pragma unroll
        for (int dt = 0; dt < 4; ++dt) {
            const int d = dt * 32 + l31;
            const int rowb = d * 128;
            const int sw = (d & 7) << 4;
#pragma unroll
            for (int kc = 0; kc < 2; ++kc) {
                const int jc = wk * 4 + kc * 2 + hi;
                bf16x8 vf = *(const bf16x8*)(vbuf + rowb + ((jc << 4) ^ sw));
                oacc[dt] = __builtin_amdgcn_mfma_f32_32x32x16_bf16(pa[kc], vf, oacc[dt], 0, 0, 0);
            }
        }
        __builtin_amdgcn_s_setprio(0);

        // UNNORMALIZED attn store from saved fr words
        float* arow = attn_row + kbase;
#pragma unroll
        for (int kc = 0; kc < 2; ++kc) {
            const u32x4 fr = frs[kc];
            f32x4 s0, s1;
            s0[0] = __builtin_bit_cast(float, fr[0] << 16);
            s0[1] = __builtin_bit_cast(float, fr[0] & 0xffff0000u);
            s0[2] = __builtin_bit_cast(float, fr[1] << 16);
            s0[3] = __builtin_bit_cast(float, fr[1] & 0xffff0000u);
            s1[0] = __builtin_bit_cast(float, fr[2] << 16);
            s1[1] = __builtin_bit_cast(float, fr[2] & 0xffff0000u);
            s1[2] = __builtin_bit_cast(float, fr[3] << 16);
            s1[3] = __builtin_bit_cast(float, fr[3] & 0xffff0000u);
            *(f32x4*)(arow + kc * 16 + hi * 8) = s0;
            *(f32x4*)(arow + kc * 16 + hi * 8 + 4) = s1;
        }
        __builtin_amdgcn_sched_barrier(0);
        __builtin_amdgcn_s_barrier();
        buf ^= 1;
    }

    // ============ epilogue ============
    // combine row sums (hi halves then wk halves via LDS)
    sumA += __shfl_xor(sumA, 32, 64);
    __syncthreads();                       // drains vmcnt (attn stores) + all LDS reads done
    float* sums   = (float*)lds;           // floats [0,128)
    float* invl64 = (float*)(lds + 512);   // floats [128,192)
    float* red    = (float*)(lds + 8192);  // 32 KB
    if (!hi) sums[(wq * 2 + wk) * 32 + l31] = sumA;
    __syncthreads();
    const float invl_l = 1.f / (sums[(wq * 2 + 0) * 32 + l31] + sums[(wq * 2 + 1) * 32 + l31]);
    if (wk == 0 && !hi) invl64[wq * 32 + l31] = invl_l;
    if (wk) {
#pragma unroll
        for (int dt = 0; dt < 4; ++dt)
#pragma unroll
            for (int r = 0; r < 16; ++r) {
                const int qr = (r & 3) + 8 * (r >> 2) + 4 * hi;
                red[wq * 4096 + qr * 128 + dt * 32 + l31] = oacc[dt][r];
            }
    }
    __syncthreads();
    if (!wk) {   // O = (partial0 + partial1) * invl
        float iv[16];
#pragma unroll
        for (int r = 0; r < 16; ++r) {
            const int qr = (r & 3) + 8 * (r >> 2) + 4 * hi;
            iv[r] = __shfl(invl_l, qr, 64);
        }
        float* ob = outg + ((long)b * S_ + q0 + wq * 32) * D_;
#pragma unroll
        for (int dt = 0; dt < 4; ++dt)
#pragma unroll
            for (int r = 0; r < 16; ++r) {
                const int qr = (r & 3) + 8 * (r >> 2) + 4 * hi;
                ob[(long)qr * D_ + dt * 32 + l31] =
                    (oacc[dt][r] + red[wq * 4096 + qr * 128 + dt * 32 + l31]) * iv[r];
            }
    }

    // in-place normalize this block's own attn region (mostly L2-resident)
    {
        const int nchunk = nt * 16;        // f32x4 chunks per row
        float* base = attng + ((long)b * S_ + q0 + w * 16) * S_;
        for (int r = 0; r < 16; ++r) {
            const float iv = invl64[w * 16 + r];
            float* ar = base + (long)r * S_;
            for (int c = lane; c < nchunk; c += 64) {
                f32x4 v = *(const f32x4*)(ar + c * 4);
                v[0] *= iv; v[1] *= iv; v[2] *= iv; v[3] *= iv;
                *(f32x4*)(ar + c * 4) = v;
            }
        }
    }

    // balanced zero-fill of this q-tile's masked region
    {
        const int col0 = nt * 64;
        if (col0 < S_) {
            const int nch = (S_ - col0) >> 2;
            const f32x4 z = {0.f, 0.f, 0.f, 0.f};
            float* fb = attng + ((long)b * S_ + q0) * S_ + col0;
            for (int row = w; row < 64; row += 4) {
                float* rb = fb + (long)row * S_;
                for (int c = lane; c < nch; c += 64)
                    *(f32x4*)(rb + c * 4) = z;
            }
        }
    }
}

// ---------------- tiny-ws fallback (validated round-2 kernel) ----------------
__global__ __launch_bounds__(256, 2)
void attn_fallback(const float* __restrict__ qg, const float* __restrict__ kg,
                   const float* __restrict__ vg,
                   float* __restrict__ outg, float* __restrict__ attng)
{
    __shared__ unsigned short kT[64 * 128];
    __shared__ unsigned short vT[128 * 64];
    __shared__ unsigned short pT[4][16 * 64];
    const int tid = threadIdx.x, lane = tid & 63, w = tid >> 6;
    const int l15 = lane & 15, l4 = lane >> 4;
    const int bid = blockIdx.x;
    const int b = bid >> 5, qt = 31 - (bid & 31), q0 = qt * 64;
    const float scale = 0.088388347648318447f;
    bf16x8 qf[4];
    {
        const float* qrow = qg + ((long)b * S_ + q0 + w * 16 + l15) * D_;
#pragma unroll
        for (int kk = 0; kk < 4; ++kk) {
            const int d0 = kk * 32 + l4 * 8;
            f32x4 a = *(const f32x4*)(qrow + d0);
            f32x4 c = *(const f32x4*)(qrow + d0 + 4);
            bf16x8 t;
            t[0] = (short)f2bf(a[0]); t[1] = (short)f2bf(a[1]);
            t[2] = (short)f2bf(a[2]); t[3] = (short)f2bf(a[3]);
            t[4] = (short)f2bf(c[0]); t[5] = (short)f2bf(c[1]);
            t[6] = (short)f2bf(c[2]); t[7] = (short)f2bf(c[3]);
            qf[kk] = t;
        }
    }
    float m[4], l[4];
#pragma unroll
    for (int r = 0; r < 4; ++r) { m[r] = -1e30f; l[r] = 0.f; }
    for (int kt = 0; kt <= qt; ++kt) {
        __syncthreads();
        {
            const float* kbase = kg + ((long)b * S_ + kt * 64) * D_;
#pragma unroll
            for (int it = 0; it < 8; ++it) {
                const int c = tid + it * 256, row = c >> 5, dc = c & 31;
                f32x4 a = *(const f32x4*)(kbase + row * D_ + dc * 4);
                u32x2 p;
                p[0] = (unsigned)f2bf(a[0]) | ((unsigned)f2bf(a[1]) << 16);
                p[1] = (unsigned)f2bf(a[2]) | ((unsigned)f2bf(a[3]) << 16);
                *(u32x2*)((char*)kT + row * 256 + ((dc * 8) ^ ((row & 7) << 4))) = p;
            }
        }
        __syncthreads();
        f32x4 acc[4];
#pragma unroll
        for (int n = 0; n < 4; ++n) {
            f32x4 a = {0.f, 0.f, 0.f, 0.f};
            const int krow = n * 16 + l15, rb = krow * 256, swz = (krow & 7) << 4;
#pragma unroll
            for (int kk = 0; kk < 4; ++kk) {
                bf16x8 bf = *(const bf16x8*)((const char*)kT + rb + ((l4 * 16 + kk * 64) ^ swz));
                a = __builtin_amdgcn_mfma_f32_16x16x32_bf16(qf[kk], bf, a, 0, 0, 0);
            }
            acc[n] = a;
        }
        const bool diag = (kt == qt);
        float tm[4] = {-3e38f, -3e38f, -3e38f, -3e38f};
#pragma unroll
        for (int n = 0; n < 4; ++n)
#pragma unroll
            for (int r = 0; r < 4; ++r) {
                float s = acc[n][r] * scale;
                if (diag && (n * 16 + l15 > w * 16 + l4 * 4 + r)) s = -3e38f;
                acc[n][r] = s; tm[r] = fmaxf(tm[r], s);
            }
#pragma unroll
        for (int off = 1; off < 16; off <<= 1)
#pragma unroll
            for (int r = 0; r < 4; ++r) tm[r] = fmaxf(tm[r], __shfl_xor(tm[r], off, 64));
        float sum[4], mn[4];
#pragma unroll
        for (int r = 0; r < 4; ++r) {
            mn[r] = fmaxf(m[r], tm[r]);
            float s0 = 0.f;
#pragma unroll
            for (int n = 0; n < 4; ++n) s0 += __expf(acc[n][r] - mn[r]);
            sum[r] = s0;
        }
#pragma unroll
        for (int off = 1; off < 16; off <<= 1)
#pragma unroll
            for (int r = 0; r < 4; ++r) sum[r] += __shfl_xor(sum[r], off, 64);
#pragma unroll
        for (int r = 0; r < 4; ++r) { l[r] = l[r] * __expf(m[r] - mn[r]) + sum[r]; m[r] = mn[r]; }
    }
    float invl[4];
#pragma unroll
    for (int r = 0; r < 4; ++r) invl[r] = 1.f / l[r];
    f32x4 oacc[8];
#pragma unroll
    for (int n = 0; n < 8; ++n) oacc[n] = (f32x4){0.f, 0.f, 0.f, 0.f};
    float* attn_base = attng + ((long)b * S_ + q0) * S_;
    for (int kt = 0; kt <= qt; ++kt) {
        __syncthreads();
        {
            const float* kbase = kg + ((long)b * S_ + kt * 64) * D_;
#pragma unroll
            for (int it = 0; it < 8; ++it) {
                const int c = tid + it * 256, row = c >> 5, dc = c & 31;
                f32x4 a = *(const f32x4*)(kbase + row * D_ + dc * 4);
                u32x2 p;
                p[0] = (unsigned)f2bf(a[0]) | ((unsigned)f2bf(a[1]) << 16);
                p[1] = (unsigned)f2bf(a[2]) | ((unsigned)f2bf(a[3]) << 16);
                *(u32x2*)((char*)kT + row * 256 + ((dc * 8) ^ ((row & 7) << 4))) = p;
            }
        }
        {
            const float* vbase = vg + ((long)b * S_ + kt * 64) * D_;
#pragma unroll
            for (int it = 0; it < 8; ++it) {
                const int c = tid + it * 256, kr = c & 63, dq = c >> 6;
                f32x4 a = *(const f32x4*)(vbase + kr * D_ + dq * 4);
#pragma unroll
                for (int j = 0; j < 4; ++j) {
                    const int d = dq * 4 + j;
                    *(unsigned short*)((char*)vT + d * 128 + ((kr * 2) ^ ((d & 7) << 4))) = f2bf(a[j]);
                }
            }
        }
        __syncthreads();
        f32x4 acc[4];
#pragma unroll
        for (int n = 0; n < 4; ++n) {
            f32x4 a = {0.f, 0.f, 0.f, 0.f};
            const int krow = n * 16 + l15, rb = krow * 256, swz = (krow & 7) << 4;
#pragma unroll
            for (int kk = 0; kk < 4; ++kk) {
                bf16x8 bf = *(const bf16x8*)((const char*)kT + rb + ((l4 * 16 + kk * 64) ^ swz));
                a = __builtin_amdgcn_mfma_f32_16x16x32_bf16(qf[kk], bf, a, 0, 0, 0);
            }
            acc[n] = a;
        }
        const bool diag = (kt == qt);
#pragma unroll
        for (int n = 0; n < 4; ++n)
#pragma unroll
            for (int r = 0; r < 4; ++r) {
                float s = acc[n][r] * scale;
                if (diag && (n * 16 + l15 > w * 16 + l4 * 4 + r)) s = -3e38f;
                const float p = __expf(s - m[r]) * invl[r];
                attn_base[(long)(w * 16 + l4 * 4 + r) * S_ + kt * 64 + n * 16 + l15] = p;
                const int prow = l4 * 4 + r;
                *(unsigned short*)((char*)&pT[w][0] + prow * 128 + ((n * 32 + l15 * 2) ^ ((prow & 7) << 4))) = f2bf(p);
            }
        asm volatile("s_waitcnt lgkmcnt(0)" ::: "memory");
        __builtin_amdgcn_sched_barrier(0);
        bf16x8 pa[2];
#pragma unroll
        for (int kk = 0; kk < 2; ++kk)
            pa[kk] = *(const bf16x8*)((const char*)&pT[w][0] + l15 * 128 + ((l4 * 16 + kk * 64) ^ ((l15 & 7) << 4)));
#pragma unroll
        for (int n = 0; n < 8; ++n) {
            const int vrow = n * 16 + l15, rb = vrow * 128, swz = (vrow & 7) << 4;
#pragma unroll
            for (int kk = 0; kk < 2; ++kk) {
                bf16x8 bv = *(const bf16x8*)((const char*)vT + rb + ((l4 * 16 + kk * 64) ^ swz));
                oacc[n] = __builtin_amdgcn_mfma_f32_16x16x32_bf16(pa[kk], bv, oacc[n], 0, 0, 0);
            }
        }
    }
    {
        float* obase = outg + ((long)b * S_ + q0 + w * 16) * D_;
#pragma unroll
        for (int n = 0; n < 8; ++n)
#pragma unroll
            for (int r = 0; r < 4; ++r)
                obase[(long)(l4 * 4 + r) * D_ + n * 16 + l15] = oacc[n][r];
    }
    {
        const int col0 = (qt + 1) * 64;
        if (col0 < S_) {
            const int nch = (S_ - col0) >> 2;
            const f32x4 z = {0.f, 0.f, 0.f, 0.f};
            for (int row = w; row < 64; row += 4) {
                float* rbase = attn_base + (long)row * S_ + col0;
                for (int c = lane; c < nch; c += 64)
                    *(f32x4*)(rbase + c * 4) = z;
            }
        }
    }
}

extern "C" void kernel_launch(void* const* d_in, const int* in_sizes, int n_in,
                              void* d_out, int out_size, void* d_ws, size_t ws_size,
                              hipStream_t stream) {
    const float* q = (const float*)d_in[0];
    const float* k = (const float*)d_in[1];
    const float* v = (const float*)d_in[2];
    float* out  = (float*)d_out;
    float* attn = out + (long)B_ * S_ * D_;
    const size_t NEED = 2u * 8388608u;   // kws + vws = 16.8 MB
    if (ws_size >= NEED) {
        char* kws = (char*)d_ws;
        char* vws = kws + 8388608;
        conv_kv<<<dim3(1024), dim3(256), 0, stream>>>(k, v, kws, vws);
        flash_single<<<dim3(512), dim3(256), 0, stream>>>(q, kws, vws, out, attn);
    } else {
        attn_fallback<<<dim3(512), dim3(256), 0, stream>>>(q, k, v, out, attn);
    }
}

// Round 14
// 116.601 us; speedup vs baseline: 1.1995x; 1.1995x over previous
//
#include <hip/hip_runtime.h>

#define B_ 16
#define S_ 2048
#define D_ 128

typedef __attribute__((ext_vector_type(8))) short bf16x8;
typedef __attribute__((ext_vector_type(4))) float f32x4;
typedef __attribute__((ext_vector_type(16))) float f32x16;
typedef __attribute__((ext_vector_type(2))) unsigned int u32x2;
typedef __attribute__((ext_vector_type(4))) unsigned int u32x4;

__device__ __forceinline__ unsigned short f2bf(float f) {
    unsigned int u = __builtin_bit_cast(unsigned int, f);
    u += 0x7fff + ((u >> 16) & 1);   // RNE
    return (unsigned short)(u >> 16);
}

__device__ __forceinline__ void gload16(const void* g, void* l) {
    __builtin_amdgcn_global_load_lds(
        (const __attribute__((address_space(1))) void*)g,
        (__attribute__((address_space(3))) void*)l, 16, 0, 0);
}

#define WAITV(n) asm volatile("s_waitcnt vmcnt(" #n ")" ::: "memory")

// T1: XCD-aware bijective swizzle (512 blocks, 8 XCDs -> XCD x owns batches {2x,2x+1}
//     -> per-XCD K/V working set 4MB = L2 fit)
__device__ __forceinline__ int xcd_swz(int raw) { return (raw & 7) * 64 + (raw >> 3); }

// ============ kernel 1: convert K & V -> bf16 swizzled tiles ============
// K tile (b*32+kt): row r, 16B chunk j at byte r*256 + ((j ^ (r&7))<<4)
// V tile: TRANSPOSED [d][kcol]: row d, chunk jc at byte d*128 + ((jc ^ (d&7))<<4)
__global__ __launch_bounds__(256, 4)
void conv_kv(const float* __restrict__ kg, const float* __restrict__ vg,
             char* __restrict__ kws, char* __restrict__ vws)
{
    __shared__ float lt[64 * 132];
    const int raw = blockIdx.x;
    const int tid = threadIdx.x;
    if (raw < 512) {                                // ---- K path ----
        const int bid = xcd_swz(raw);
        const float* src = kg + ((long)bid << 13);
        char* dst = kws + ((long)bid << 14);
#pragma unroll
        for (int it = 0; it < 4; ++it) {
            const int c = tid + it * 256;
            const int r = c >> 4, j = c & 15;
            f32x4 a = *(const f32x4*)(src + r * 128 + j * 8);
            f32x4 cc = *(const f32x4*)(src + r * 128 + j * 8 + 4);
            u32x4 p;
            p[0] = (unsigned)f2bf(a[0]) | ((unsigned)f2bf(a[1]) << 16);
            p[1] = (unsigned)f2bf(a[2]) | ((unsigned)f2bf(a[3]) << 16);
            p[2] = (unsigned)f2bf(cc[0]) | ((unsigned)f2bf(cc[1]) << 16);
            p[3] = (unsigned)f2bf(cc[2]) | ((unsigned)f2bf(cc[3]) << 16);
            *(u32x4*)(dst + r * 256 + ((j ^ (r & 7)) << 4)) = p;
        }
    } else {                                        // ---- V path (transposed) ----
        const int vb = xcd_swz(raw - 512);
        const float* src = vg + ((long)vb << 13);
        char* dst = vws + ((long)vb << 14);
#pragma unroll
        for (int it = 0; it < 8; ++it) {
            const int c = tid + it * 256;
            const int r = c >> 5, q = c & 31;
            *(f32x4*)(lt + r * 132 + q * 4) = *(const f32x4*)(src + r * 128 + q * 4);
        }
        __syncthreads();
#pragma unroll
        for (int it = 0; it < 4; ++it) {
            const int c = tid + it * 256;
            const int d = c >> 3, jc = c & 7;
            unsigned short e[8];
#pragma unroll
            for (int ee = 0; ee < 8; ++ee) e[ee] = f2bf(lt[(jc * 8 + ee) * 132 + d]);
            u32x4 p;
            p[0] = (unsigned)e[0] | ((unsigned)e[1] << 16);
            p[1] = (unsigned)e[2] | ((unsigned)e[3] << 16);
            p[2] = (unsigned)e[4] | ((unsigned)e[5] << 16);
            p[3] = (unsigned)e[6] | ((unsigned)e[7] << 16);
            *(u32x4*)(dst + d * 128 + ((jc ^ (d & 7)) << 4)) = p;
        }
    }
}

// balanced q-tile map: co-resident raw i,i+256 -> logical (b,t),(b+1,t); flip on b&1
__device__ __forceinline__ int qtile_of(int b, int t) {
    const int f = (t & 1) ? (t >> 1) : (31 - (t >> 1));
    return (b & 1) ? (31 - f) : f;
}

// ============ kernel 2: fused flash — barrier-free reg-based loop A + r12 loop B ============
__global__ __launch_bounds__(256, 2)
void flash_fused(const float* __restrict__ qg, const char* __restrict__ kws,
                 const char* __restrict__ vws,
                 float* __restrict__ outg, float* __restrict__ attng)
{
    __shared__ char lds[65536];   // loop B: K dbuf @0/16384, V dbuf @32768/49152; sums/red alias @0

    const int tid = threadIdx.x, lane = tid & 63, w = tid >> 6;
    const int wq = w >> 1, wk = w & 1;
    const int l31 = lane & 31, hi = lane >> 5;
    const int bid = xcd_swz(blockIdx.x);
    const int b = bid >> 5;
    const int qt = qtile_of(b, bid & 31);
    const int q0 = qt * 64;
    const int nt = qt + 1;
    const float scale = 0.088388347648318447f;
    const int qrow = q0 + wq * 32 + l31;

    bf16x8 qf[8];
    {
        const float* qr = qg + ((long)b * S_ + qrow) * D_;
#pragma unroll
        for (int km = 0; km < 8; ++km) {
            const int d0 = km * 16 + hi * 8;
            f32x4 a = *(const f32x4*)(qr + d0);
            f32x4 c = *(const f32x4*)(qr + d0 + 4);
            bf16x8 t;
            t[0] = (short)f2bf(a[0]); t[1] = (short)f2bf(a[1]);
            t[2] = (short)f2bf(a[2]); t[3] = (short)f2bf(a[3]);
            t[4] = (short)f2bf(c[0]); t[5] = (short)f2bf(c[1]);
            t[6] = (short)f2bf(c[2]); t[7] = (short)f2bf(c[3]);
            qf[km] = t;
        }
    }

    const char* kb0 = kws + ((long)(b * 32) << 14);
    const char* vb0 = vws + ((long)(b * 32) << 14);
    const int krow = wk * 32 + l31;
    const int krb = krow * 256;
    const int ksw = krow & 7;

    // ========== LOOP A: row sums — K straight from L2 to regs, NO LDS, NO barriers ==========
    float sumA = 0.f;
    {
        bf16x8 kf[8];
#pragma unroll
        for (int km = 0; km < 8; ++km)
            kf[km] = *(const bf16x8*)(kb0 + krb + (((km * 2 + hi) ^ ksw) << 4));
        for (int kt = 0; kt < nt; ++kt) {
            f32x16 a0, a1;
#pragma unroll
            for (int i = 0; i < 16; ++i) { a0[i] = 0.f; a1[i] = 0.f; }
            __builtin_amdgcn_s_setprio(1);
#pragma unroll
            for (int km = 0; km < 8; ++km) {
                if (km & 1) a1 = __builtin_amdgcn_mfma_f32_32x32x16_bf16(kf[km], qf[km], a1, 0, 0, 0);
                else        a0 = __builtin_amdgcn_mfma_f32_32x32x16_bf16(kf[km], qf[km], a0, 0, 0, 0);
            }
            __builtin_amdgcn_s_setprio(0);
            if (kt + 1 < nt) {
                const char* kn = kb0 + ((long)(kt + 1) << 14);
#pragma unroll
                for (int km = 0; km < 8; ++km)
                    kf[km] = *(const bf16x8*)(kn + krb + (((km * 2 + hi) ^ ksw) << 4));
            }
            const int kbase = kt * 64 + wk * 32;
#pragma unroll
            for (int r = 0; r < 16; ++r) {
                const int kl = (r & 3) + 8 * (r >> 2) + 4 * hi;
                if (kbase + kl <= qrow) sumA += __expf((a0[r] + a1[r]) * scale);
            }
        }
    }

    sumA += __shfl_xor(sumA, 32, 64);
    WAITV(0);   // all reg loads retired (compiler-waited); make counted vmcnt below exact
    float* sums = (float*)lds;
    if (!hi) sums[(wq * 2 + wk) * 32 + l31] = sumA;
    __syncthreads();
    const float invl_l = 1.f / (sums[(wq * 2 + 0) * 32 + l31] + sums[(wq * 2 + 1) * 32 + l31]);
    __syncthreads();   // all reads done before staging overwrites sums

    // ================= LOOP B: QK recompute + PV + attn store (r12 verbatim) =================
    f32x16 oacc[4];
#pragma unroll
    for (int dt = 0; dt < 4; ++dt)
#pragma unroll
        for (int i = 0; i < 16; ++i) oacc[dt][i] = 0.f;

    float* attn_row = attng + ((long)b * S_ + qrow) * S_;

#pragma unroll
    for (int it = 0; it < 4; ++it)
        gload16(kb0 + it * 4096 + tid * 16, lds + it * 4096 + tid * 16);
#pragma unroll
    for (int it = 0; it < 4; ++it)
        gload16(vb0 + it * 4096 + tid * 16, lds + 32768 + it * 4096 + tid * 16);

    int buf = 0;
    for (int kt = 0; kt < nt; ++kt) {
        const bool pf = (kt + 1 < nt);
        if (pf) {
            const char* kn = kb0 + ((long)(kt + 1) << 14);
            const char* vn = vb0 + ((long)(kt + 1) << 14);
            const int db = (buf ^ 1) * 16384;
#pragma unroll
            for (int it = 0; it < 4; ++it)
                gload16(kn + it * 4096 + tid * 16, lds + db + it * 4096 + tid * 16);
#pragma unroll
            for (int it = 0; it < 4; ++it)
                gload16(vn + it * 4096 + tid * 16, lds + 32768 + db + it * 4096 + tid * 16);
        }
        // per-wave FIFO: retire this tile's 8 loads; newer = (pf?8:0) loads + (kt?4:0) stores
        if (kt == 0) { if (pf) { WAITV(8); } else { WAITV(0); } }
        else         { if (pf) { WAITV(12); } else { WAITV(4); } }
        __builtin_amdgcn_s_barrier();
        __builtin_amdgcn_sched_barrier(0);

        const char* kbuf = lds + buf * 16384;
        const char* vbuf = lds + 32768 + buf * 16384;

        f32x16 a0, a1;
#pragma unroll
        for (int i = 0; i < 16; ++i) { a0[i] = 0.f; a1[i] = 0.f; }
        __builtin_amdgcn_s_setprio(1);
#pragma unroll
        for (int km = 0; km < 8; ++km) {
            bf16x8 kf = *(const bf16x8*)(kbuf + krb + (((km * 2 + hi) ^ ksw) << 4));
            if (km & 1) a1 = __builtin_amdgcn_mfma_f32_32x32x16_bf16(kf, qf[km], a1, 0, 0, 0);
            else        a0 = __builtin_amdgcn_mfma_f32_32x32x16_bf16(kf, qf[km], a0, 0, 0, 0);
        }
        __builtin_amdgcn_s_setprio(0);

        // softmax numerators + bf16 pack
        const int kbase = kt * 64 + wk * 32;
        unsigned W[8], PW[8];
#pragma unroll
        for (int i = 0; i < 8; ++i) {
            const int r0 = 2 * i;
            const int kl0 = (r0 & 3) + 8 * (r0 >> 2) + 4 * hi;
            const float p0 = (kbase + kl0 > qrow) ? 0.f : __expf((a0[r0] + a1[r0]) * scale);
            const float p1 = (kbase + kl0 + 1 > qrow) ? 0.f : __expf((a0[r0 + 1] + a1[r0 + 1]) * scale);
            W[i] = (unsigned)f2bf(p0) | ((unsigned)f2bf(p1) << 16);
        }
#pragma unroll
        for (int i = 0; i < 8; ++i)
            PW[i] = (unsigned)__shfl_xor((int)W[i], 32, 64);

        // PV A-frags
        bf16x8 pa[2];
        u32x4 frs[2];
#pragma unroll
        for (int kc = 0; kc < 2; ++kc) {
            u32x4 fr;
            fr[0] = hi ? PW[kc * 4 + 2] : W[kc * 4 + 0];
            fr[1] = hi ? PW[kc * 4 + 3] : W[kc * 4 + 1];
            fr[2] = hi ? W[kc * 4 + 2] : PW[kc * 4 + 0];
            fr[3] = hi ? W[kc * 4 + 3] : PW[kc * 4 + 1];
            frs[kc] = fr;
            pa[kc] = __builtin_bit_cast(bf16x8, fr);
        }

        // PV first (matrix pipe), attn stores issue under it
        __builtin_amdgcn_s_setprio(1);
#pragma unroll
        for (int dt = 0; dt < 4; ++dt) {
            const int d = dt * 32 + l31;
            const int rowb = d * 128;
            const int sw = (d & 7) << 4;
#pragma unroll
            for (int kc = 0; kc < 2; ++kc) {
                const int jc = wk * 4 + kc * 2 + hi;
                bf16x8 vf = *(const bf16x8*)(vbuf + rowb + ((jc << 4) ^ sw));
                oacc[dt] = __builtin_amdgcn_mfma_f32_32x32x16_bf16(pa[kc], vf, oacc[dt], 0, 0, 0);
            }
        }
        __builtin_amdgcn_s_setprio(0);

        // normalized attn store from saved fr words
        float* arow = attn_row + kbase;
#pragma unroll
        for (int kc = 0; kc < 2; ++kc) {
            const u32x4 fr = frs[kc];
            f32x4 s0, s1;
            s0[0] = __builtin_bit_cast(float, fr[0] << 16) * invl_l;
            s0[1] = __builtin_bit_cast(float, fr[0] & 0xffff0000u) * invl_l;
            s0[2] = __builtin_bit_cast(float, fr[1] << 16) * invl_l;
            s0[3] = __builtin_bit_cast(float, fr[1] & 0xffff0000u) * invl_l;
            s1[0] = __builtin_bit_cast(float, fr[2] << 16) * invl_l;
            s1[1] = __builtin_bit_cast(float, fr[2] & 0xffff0000u) * invl_l;
            s1[2] = __builtin_bit_cast(float, fr[3] << 16) * invl_l;
            s1[3] = __builtin_bit_cast(float, fr[3] & 0xffff0000u) * invl_l;
            *(f32x4*)(arow + kc * 16 + hi * 8) = s0;
            *(f32x4*)(arow + kc * 16 + hi * 8 + 4) = s1;
        }
        __builtin_amdgcn_sched_barrier(0);
        __builtin_amdgcn_s_barrier();
        buf ^= 1;
    }

    // epilogue: reduce wk halves' partial O through LDS, normalize, store
    __syncthreads();
    float* red = (float*)lds;
    if (wk) {
#pragma unroll
        for (int dt = 0; dt < 4; ++dt)
#pragma unroll
            for (int r = 0; r < 16; ++r) {
                const int qr = (r & 3) + 8 * (r >> 2) + 4 * hi;
                red[wq * 4096 + qr * 128 + dt * 32 + l31] = oacc[dt][r];
            }
    }
    __syncthreads();
    if (!wk) {
        float iv[16];
#pragma unroll
        for (int r = 0; r < 16; ++r) {
            const int qr = (r & 3) + 8 * (r >> 2) + 4 * hi;
            iv[r] = __shfl(invl_l, qr, 64);
        }
        float* ob = outg + ((long)b * S_ + q0 + wq * 32) * D_;
#pragma unroll
        for (int dt = 0; dt < 4; ++dt)
#pragma unroll
            for (int r = 0; r < 16; ++r) {
                const int qr = (r & 3) + 8 * (r >> 2) + 4 * hi;
                ob[(long)qr * D_ + dt * 32 + l31] =
                    (oacc[dt][r] + red[wq * 4096 + qr * 128 + dt * 32 + l31]) * iv[r];
            }
    }

    // balanced zero-fill of this q-tile's masked region
    {
        const int col0 = nt * 64;
        if (col0 < S_) {
            const int nch = (S_ - col0) >> 2;
            const f32x4 z = {0.f, 0.f, 0.f, 0.f};
            float* fb = attng + ((long)b * S_ + q0) * S_ + col0;
            for (int row = w; row < 64; row += 4) {
                float* rb = fb + (long)row * S_;
                for (int c = lane; c < nch; c += 64)
                    *(f32x4*)(rb + c * 4) = z;
            }
        }
    }
}

// ---------------- tiny-ws fallback (validated round-2 kernel) ----------------
__global__ __launch_bounds__(256, 2)
void attn_fallback(const float* __restrict__ qg, const float* __restrict__ kg,
                   const float* __restrict__ vg,
                   float* __restrict__ outg, float* __restrict__ attng)
{
    __shared__ unsigned short kT[64 * 128];
    __shared__ unsigned short vT[128 * 64];
    __shared__ unsigned short pT[4][16 * 64];
    const int tid = threadIdx.x, lane = tid & 63, w = tid >> 6;
    const int l15 = lane & 15, l4 = lane >> 4;
    const int bid = blockIdx.x;
    const int b = bid >> 5, qt = 31 - (bid & 31), q0 = qt * 64;
    const float scale = 0.088388347648318447f;
    bf16x8 qf[4];
    {
        const float* qrow = qg + ((long)b * S_ + q0 + w * 16 + l15) * D_;
#pragma unroll
        for (int kk = 0; kk < 4; ++kk) {
            const int d0 = kk * 32 + l4 * 8;
            f32x4 a = *(const f32x4*)(qrow + d0);
            f32x4 c = *(const f32x4*)(qrow + d0 + 4);
            bf16x8 t;
            t[0] = (short)f2bf(a[0]); t[1] = (short)f2bf(a[1]);
            t[2] = (short)f2bf(a[2]); t[3] = (short)f2bf(a[3]);
            t[4] = (short)f2bf(c[0]); t[5] = (short)f2bf(c[1]);
            t[6] = (short)f2bf(c[2]); t[7] = (short)f2bf(c[3]);
            qf[kk] = t;
        }
    }
    float m[4], l[4];
#pragma unroll
    for (int r = 0; r < 4; ++r) { m[r] = -1e30f; l[r] = 0.f; }
    for (int kt = 0; kt <= qt; ++kt) {
        __syncthreads();
        {
            const float* kbase = kg + ((long)b * S_ + kt * 64) * D_;
#pragma unroll
            for (int it = 0; it < 8; ++it) {
                const int c = tid + it * 256, row = c >> 5, dc = c & 31;
                f32x4 a = *(const f32x4*)(kbase + row * D_ + dc * 4);
                u32x2 p;
                p[0] = (unsigned)f2bf(a[0]) | ((unsigned)f2bf(a[1]) << 16);
                p[1] = (unsigned)f2bf(a[2]) | ((unsigned)f2bf(a[3]) << 16);
                *(u32x2*)((char*)kT + row * 256 + ((dc * 8) ^ ((row & 7) << 4))) = p;
            }
        }
        __syncthreads();
        f32x4 acc[4];
#pragma unroll
        for (int n = 0; n < 4; ++n) {
            f32x4 a = {0.f, 0.f, 0.f, 0.f};
            const int krow = n * 16 + l15, rb = krow * 256, swz = (krow & 7) << 4;
#pragma unroll
            for (int kk = 0; kk < 4; ++kk) {
                bf16x8 bf = *(const bf16x8*)((const char*)kT + rb + ((l4 * 16 + kk * 64) ^ swz));
                a = __builtin_amdgcn_mfma_f32_16x16x32_bf16(qf[kk], bf, a, 0, 0, 0);
            }
            acc[n] = a;
        }
        const bool diag = (kt == qt);
        float tm[4] = {-3e38f, -3e38f, -3e38f, -3e38f};
#pragma unroll
        for (int n = 0; n < 4; ++n)
#pragma unroll
            for (int r = 0; r < 4; ++r) {
                float s = acc[n][r] * scale;
                if (diag && (n * 16 + l15 > w * 16 + l4 * 4 + r)) s = -3e38f;
                acc[n][r] = s; tm[r] = fmaxf(tm[r], s);
            }
#pragma unroll
        for (int off = 1; off < 16; off <<= 1)
#pragma unroll
            for (int r = 0; r < 4; ++r) tm[r] = fmaxf(tm[r], __shfl_xor(tm[r], off, 64));
        float sum[4], mn[4];
#pragma unroll
        for (int r = 0; r < 4; ++r) {
            mn[r] = fmaxf(m[r], tm[r]);
            float s0 = 0.f;
#pragma unroll
            for (int n = 0; n < 4; ++n) s0 += __expf(acc[n][r] - mn[r]);
            sum[r] = s0;
        }
#pragma unroll
        for (int off = 1; off < 16; off <<= 1)
#pragma unroll
            for (int r = 0; r < 4; ++r) sum[r] += __shfl_xor(sum[r], off, 64);
#pragma unroll
        for (int r = 0; r < 4; ++r) { l[r] = l[r] * __expf(m[r] - mn[r]) + sum[r]; m[r] = mn[r]; }
    }
    float invl[4];
#pragma unroll
    for (int r = 0; r < 4; ++r) invl[r] = 1.f / l[r];
    f32x4 oacc[8];
#pragma unroll
    for (int n = 0; n < 8; ++n) oacc[n] = (f32x4){0.f, 0.f, 0.f, 0.f};
    float* attn_base = attng + ((long)b * S_ + q0) * S_;
    for (int kt = 0; kt <= qt; ++kt) {
        __syncthreads();
        {
            const float* kbase = kg + ((long)b * S_ + kt * 64) * D_;
#pragma unroll
            for (int it = 0; it < 8; ++it) {
                const int c = tid + it * 256, row = c >> 5, dc = c & 31;
                f32x4 a = *(const f32x4*)(kbase + row * D_ + dc * 4);
                u32x2 p;
                p[0] = (unsigned)f2bf(a[0]) | ((unsigned)f2bf(a[1]) << 16);
                p[1] = (unsigned)f2bf(a[2]) | ((unsigned)f2bf(a[3]) << 16);
                *(u32x2*)((char*)kT + row * 256 + ((dc * 8) ^ ((row & 7) << 4))) = p;
            }
        }
        {
            const float* vbase = vg + ((long)b * S_ + kt * 64) * D_;
#pragma unroll
            for (int it = 0; it < 8; ++it) {
                const int c = tid + it * 256, kr = c & 63, dq = c >> 6;
                f32x4 a = *(const f32x4*)(vbase + kr * D_ + dq * 4);
#pragma unroll
                for (int j = 0; j < 4; ++j) {
                    const int d = dq * 4 + j;
                    *(unsigned short*)((char*)vT + d * 128 + ((kr * 2) ^ ((d & 7) << 4))) = f2bf(a[j]);
                }
            }
        }
        __syncthreads();
        f32x4 acc[4];
#pragma unroll
        for (int n = 0; n < 4; ++n) {
            f32x4 a = {0.f, 0.f, 0.f, 0.f};
            const int krow = n * 16 + l15, rb = krow * 256, swz = (krow & 7) << 4;
#pragma unroll
            for (int kk = 0; kk < 4; ++kk) {
                bf16x8 bf = *(const bf16x8*)((const char*)kT + rb + ((l4 * 16 + kk * 64) ^ swz));
                a = __builtin_amdgcn_mfma_f32_16x16x32_bf16(qf[kk], bf, a, 0, 0, 0);
            }
            acc[n] = a;
        }
        const bool diag = (kt == qt);
#pragma unroll
        for (int n = 0; n < 4; ++n)
#pragma unroll
            for (int r = 0; r < 4; ++r) {
                float s = acc[n][r] * scale;
                if (diag && (n * 16 + l15 > w * 16 + l4 * 4 + r)) s = -3e38f;
                const float p = __expf(s - m[r]) * invl[r];
                attn_base[(long)(w * 16 + l4 * 4 + r) * S_ + kt * 64 + n * 16 + l15] = p;
                const int prow = l4 * 4 + r;
                *(unsigned short*)((char*)&pT[w][0] + prow * 128 + ((n * 32 + l15 * 2) ^ ((prow & 7) << 4))) = f2bf(p);
            }
        asm volatile("s_waitcnt lgkmcnt(0)" ::: "memory");
        __builtin_amdgcn_sched_barrier(0);
        bf16x8 pa[2];
#pragma unroll
        for (int kk = 0; kk < 2; ++kk)
            pa[kk] = *(const bf16x8*)((const char*)&pT[w][0] + l15 * 128 + ((l4 * 16 + kk * 64) ^ ((l15 & 7) << 4)));
#pragma unroll
        for (int n = 0; n < 8; ++n) {
            const int vrow = n * 16 + l15, rb = vrow * 128, swz = (vrow & 7) << 4;
#pragma unroll
            for (int kk = 0; kk < 2; ++kk) {
                bf16x8 bv = *(const bf16x8*)((const char*)vT + rb + ((l4 * 16 + kk * 64) ^ swz));
                oacc[n] = __builtin_amdgcn_mfma_f32_16x16x32_bf16(pa[kk], bv, oacc[n], 0, 0, 0);
            }
        }
    }
    {
        float* obase = outg + ((long)b * S_ + q0 + w * 16) * D_;
#pragma unroll
        for (int n = 0; n < 8; ++n)
#pragma unroll
            for (int r = 0; r < 4; ++r)
                obase[(long)(l4 * 4 + r) * D_ + n * 16 + l15] = oacc[n][r];
    }
    {
        const int col0 = (qt + 1) * 64;
        if (col0 < S_) {
            const int nch = (S_ - col0) >> 2;
            const f32x4 z = {0.f, 0.f, 0.f, 0.f};
            for (int row = w; row < 64; row += 4) {
                float* rbase = attn_base + (long)row * S_ + col0;
                for (int c = lane; c < nch; c += 64)
                    *(f32x4*)(rbase + c * 4) = z;
            }
        }
    }
}

extern "C" void kernel_launch(void* const* d_in, const int* in_sizes, int n_in,
                              void* d_out, int out_size, void* d_ws, size_t ws_size,
                              hipStream_t stream) {
    const float* q = (const float*)d_in[0];
    const float* k = (const float*)d_in[1];
    const float* v = (const float*)d_in[2];
    float* out  = (float*)d_out;
    float* attn = out + (long)B_ * S_ * D_;
    const size_t NEED = 2u * 8388608u;   // kws + vws = 16.8 MB
    if (ws_size >= NEED) {
        char* kws = (char*)d_ws;
        char* vws = kws + 8388608;
        conv_kv<<<dim3(1024), dim3(256), 0, stream>>>(k, v, kws, vws);
        flash_fused<<<dim3(512), dim3(256), 0, stream>>>(q, kws, vws, out, attn);
    } else {
        attn_fallback<<<dim3(512), dim3(256), 0, stream>>>(q, k, v, out, attn);
    }
}

// Round 15
// 113.082 us; speedup vs baseline: 1.2368x; 1.0311x over previous
//
#include <hip/hip_runtime.h>

#define B_ 16
#define S_ 2048
#define D_ 128

typedef __attribute__((ext_vector_type(8))) short bf16x8;
typedef __attribute__((ext_vector_type(4))) float f32x4;
typedef __attribute__((ext_vector_type(16))) float f32x16;
typedef __attribute__((ext_vector_type(2))) unsigned int u32x2;
typedef __attribute__((ext_vector_type(4))) unsigned int u32x4;

__device__ __forceinline__ unsigned short f2bf(float f) {
    unsigned int u = __builtin_bit_cast(unsigned int, f);
    u += 0x7fff + ((u >> 16) & 1);   // RNE
    return (unsigned short)(u >> 16);
}

__device__ __forceinline__ void gload16(const void* g, void* l) {
    __builtin_amdgcn_global_load_lds(
        (const __attribute__((address_space(1))) void*)g,
        (__attribute__((address_space(3))) void*)l, 16, 0, 0);
}

#define WAITV(n) asm volatile("s_waitcnt vmcnt(" #n ")" ::: "memory")

// T1: XCD-aware bijective swizzle (512 blocks, 8 XCDs -> XCD x owns batches {2x,2x+1}
//     -> per-XCD K/V working set 4MB = L2 fit)
__device__ __forceinline__ int xcd_swz(int raw) { return (raw & 7) * 64 + (raw >> 3); }

// ============ kernel 1: convert K & V -> bf16 swizzled tiles ============
// K tile (b*32+kt): row r, 16B chunk j at byte r*256 + ((j ^ (r&7))<<4)
// V tile: TRANSPOSED [d][kcol]: row d, chunk jc at byte d*128 + ((jc ^ (d&7))<<4)
__global__ __launch_bounds__(256, 4)
void conv_kv(const float* __restrict__ kg, const float* __restrict__ vg,
             char* __restrict__ kws, char* __restrict__ vws)
{
    __shared__ float lt[64 * 132];
    const int raw = blockIdx.x;
    const int tid = threadIdx.x;
    if (raw < 512) {                                // ---- K path ----
        const int bid = xcd_swz(raw);
        const float* src = kg + ((long)bid << 13);
        char* dst = kws + ((long)bid << 14);
#pragma unroll
        for (int it = 0; it < 4; ++it) {
            const int c = tid + it * 256;
            const int r = c >> 4, j = c & 15;
            f32x4 a = *(const f32x4*)(src + r * 128 + j * 8);
            f32x4 cc = *(const f32x4*)(src + r * 128 + j * 8 + 4);
            u32x4 p;
            p[0] = (unsigned)f2bf(a[0]) | ((unsigned)f2bf(a[1]) << 16);
            p[1] = (unsigned)f2bf(a[2]) | ((unsigned)f2bf(a[3]) << 16);
            p[2] = (unsigned)f2bf(cc[0]) | ((unsigned)f2bf(cc[1]) << 16);
            p[3] = (unsigned)f2bf(cc[2]) | ((unsigned)f2bf(cc[3]) << 16);
            *(u32x4*)(dst + r * 256 + ((j ^ (r & 7)) << 4)) = p;
        }
    } else {                                        // ---- V path (transposed) ----
        const int vb = xcd_swz(raw - 512);
        const float* src = vg + ((long)vb << 13);
        char* dst = vws + ((long)vb << 14);
#pragma unroll
        for (int it = 0; it < 8; ++it) {
            const int c = tid + it * 256;
            const int r = c >> 5, q = c & 31;
            *(f32x4*)(lt + r * 132 + q * 4) = *(const f32x4*)(src + r * 128 + q * 4);
        }
        __syncthreads();
#pragma unroll
        for (int it = 0; it < 4; ++it) {
            const int c = tid + it * 256;
            const int d = c >> 3, jc = c & 7;
            unsigned short e[8];
#pragma unroll
            for (int ee = 0; ee < 8; ++ee) e[ee] = f2bf(lt[(jc * 8 + ee) * 132 + d]);
            u32x4 p;
            p[0] = (unsigned)e[0] | ((unsigned)e[1] << 16);
            p[1] = (unsigned)e[2] | ((unsigned)e[3] << 16);
            p[2] = (unsigned)e[4] | ((unsigned)e[5] << 16);
            p[3] = (unsigned)e[6] | ((unsigned)e[7] << 16);
            *(u32x4*)(dst + d * 128 + ((jc ^ (d & 7)) << 4)) = p;
        }
    }
}

// balanced q-tile map: co-resident raw i,i+256 -> logical (b,t),(b+1,t); flip on b&1
__device__ __forceinline__ int qtile_of(int b, int t) {
    const int f = (t & 1) ? (t >> 1) : (31 - (t >> 1));
    return (b & 1) ? (31 - f) : f;
}

// ============ kernel 2: fused flash (paired sum pass + store/PV pass) + zero-fill ============
__global__ __launch_bounds__(256, 2)
void flash_fused(const float* __restrict__ qg, const char* __restrict__ kws,
                 const char* __restrict__ vws,
                 float* __restrict__ outg, float* __restrict__ attng)
{
    __shared__ char lds[65536];   // loop A: 2x32KB K-pair dbuf; loop B: K dbuf @0/16384, V @32768/49152

    const int tid = threadIdx.x, lane = tid & 63, w = tid >> 6;
    const int wq = w >> 1, wk = w & 1;
    const int l31 = lane & 31, hi = lane >> 5;
    const int bid = xcd_swz(blockIdx.x);
    const int b = bid >> 5;
    const int qt = qtile_of(b, bid & 31);
    const int q0 = qt * 64;
    const int nt = qt + 1;
    const float scale = 0.088388347648318447f;
    const int qrow = q0 + wq * 32 + l31;

    bf16x8 qf[8];
    {
        const float* qr = qg + ((long)b * S_ + qrow) * D_;
#pragma unroll
        for (int km = 0; km < 8; ++km) {
            const int d0 = km * 16 + hi * 8;
            f32x4 a = *(const f32x4*)(qr + d0);
            f32x4 c = *(const f32x4*)(qr + d0 + 4);
            bf16x8 t;
            t[0] = (short)f2bf(a[0]); t[1] = (short)f2bf(a[1]);
            t[2] = (short)f2bf(a[2]); t[3] = (short)f2bf(a[3]);
            t[4] = (short)f2bf(c[0]); t[5] = (short)f2bf(c[1]);
            t[6] = (short)f2bf(c[2]); t[7] = (short)f2bf(c[3]);
            qf[km] = t;
        }
    }
    WAITV(0);   // drain q loads so counted vmcnt is exact

    const char* kb0 = kws + ((long)(b * 32) << 14);
    const char* vb0 = vws + ((long)(b * 32) << 14);
    const int krow = wk * 32 + l31;
    const int krb = krow * 256;
    const int ksw = krow & 7;

    // ================= LOOP A: row sums, 2 K-tiles per phase =================
    const int np = (nt + 1) >> 1;
    {
        const char* k1 = kb0 + ((long)((nt > 1) ? 1 : 0) << 14);
#pragma unroll
        for (int it = 0; it < 4; ++it)
            gload16(kb0 + it * 4096 + tid * 16, lds + it * 4096 + tid * 16);
#pragma unroll
        for (int it = 0; it < 4; ++it)
            gload16(k1 + it * 4096 + tid * 16, lds + 16384 + it * 4096 + tid * 16);
    }
    float sumA = 0.f;
    int bufA = 0;
    for (int p = 0; p < np; ++p) {
        const bool pf = (p + 1 < np);
        if (pf) {
            const int t0 = p * 2 + 2;
            const int t1 = (t0 + 1 < nt) ? (t0 + 1) : (nt - 1);
            const char* k0 = kb0 + ((long)t0 << 14);
            const char* k1 = kb0 + ((long)t1 << 14);
            const int db = (bufA ^ 1) * 32768;
#pragma unroll
            for (int it = 0; it < 4; ++it)
                gload16(k0 + it * 4096 + tid * 16, lds + db + it * 4096 + tid * 16);
#pragma unroll
            for (int it = 0; it < 4; ++it)
                gload16(k1 + it * 4096 + tid * 16, lds + db + 16384 + it * 4096 + tid * 16);
            WAITV(8);
        } else { WAITV(0); }
        __builtin_amdgcn_s_barrier();
        __builtin_amdgcn_sched_barrier(0);

#pragma unroll
        for (int s = 0; s < 2; ++s) {
            const int kt = p * 2 + s;
            if (kt < nt) {                       // wave-uniform guard (phantom tail tile)
                const char* kbuf = lds + bufA * 32768 + s * 16384;
                f32x16 a0, a1;
#pragma unroll
                for (int i = 0; i < 16; ++i) { a0[i] = 0.f; a1[i] = 0.f; }
                __builtin_amdgcn_s_setprio(1);
#pragma unroll
                for (int km = 0; km < 8; ++km) {
                    bf16x8 kf = *(const bf16x8*)(kbuf + krb + (((km * 2 + hi) ^ ksw) << 4));
                    if (km & 1) a1 = __builtin_amdgcn_mfma_f32_32x32x16_bf16(kf, qf[km], a1, 0, 0, 0);
                    else        a0 = __builtin_amdgcn_mfma_f32_32x32x16_bf16(kf, qf[km], a0, 0, 0, 0);
                }
                __builtin_amdgcn_s_setprio(0);
                const int kbase = kt * 64 + wk * 32;
#pragma unroll
                for (int r = 0; r < 16; ++r) {
                    const int kl = (r & 3) + 8 * (r >> 2) + 4 * hi;
                    if (kbase + kl <= qrow) sumA += __expf((a0[r] + a1[r]) * scale);
                }
            }
        }
        __builtin_amdgcn_sched_barrier(0);
        __builtin_amdgcn_s_barrier();
        bufA ^= 1;
    }

    sumA += __shfl_xor(sumA, 32, 64);
    float* sums = (float*)lds;
    if (!hi) sums[(wq * 2 + wk) * 32 + l31] = sumA;
    __syncthreads();
    const float invl_l = 1.f / (sums[(wq * 2 + 0) * 32 + l31] + sums[(wq * 2 + 1) * 32 + l31]);
    __syncthreads();   // all reads done before staging overwrites sums

    // ================= LOOP B: QK recompute + PV + attn store =================
    f32x16 oacc[4];
#pragma unroll
    for (int dt = 0; dt < 4; ++dt)
#pragma unroll
        for (int i = 0; i < 16; ++i) oacc[dt][i] = 0.f;

    float* attn_row = attng + ((long)b * S_ + qrow) * S_;

#pragma unroll
    for (int it = 0; it < 4; ++it)
        gload16(kb0 + it * 4096 + tid * 16, lds + it * 4096 + tid * 16);
#pragma unroll
    for (int it = 0; it < 4; ++it)
        gload16(vb0 + it * 4096 + tid * 16, lds + 32768 + it * 4096 + tid * 16);

    int buf = 0;
    for (int kt = 0; kt < nt; ++kt) {
        const bool pf = (kt + 1 < nt);
        if (pf) {
            const char* kn = kb0 + ((long)(kt + 1) << 14);
            const char* vn = vb0 + ((long)(kt + 1) << 14);
            const int db = (buf ^ 1) * 16384;
#pragma unroll
            for (int it = 0; it < 4; ++it)
                gload16(kn + it * 4096 + tid * 16, lds + db + it * 4096 + tid * 16);
#pragma unroll
            for (int it = 0; it < 4; ++it)
                gload16(vn + it * 4096 + tid * 16, lds + 32768 + db + it * 4096 + tid * 16);
        }
        // per-wave FIFO: retire this tile's 8 loads; newer = (pf?8:0) loads + (kt?4:0) stores
        if (kt == 0) { if (pf) { WAITV(8); } else { WAITV(0); } }
        else         { if (pf) { WAITV(12); } else { WAITV(4); } }
        __builtin_amdgcn_s_barrier();
        __builtin_amdgcn_sched_barrier(0);

        const char* kbuf = lds + buf * 16384;
        const char* vbuf = lds + 32768 + buf * 16384;

        f32x16 a0, a1;
#pragma unroll
        for (int i = 0; i < 16; ++i) { a0[i] = 0.f; a1[i] = 0.f; }
        __builtin_amdgcn_s_setprio(1);
#pragma unroll
        for (int km = 0; km < 8; ++km) {
            bf16x8 kf = *(const bf16x8*)(kbuf + krb + (((km * 2 + hi) ^ ksw) << 4));
            if (km & 1) a1 = __builtin_amdgcn_mfma_f32_32x32x16_bf16(kf, qf[km], a1, 0, 0, 0);
            else        a0 = __builtin_amdgcn_mfma_f32_32x32x16_bf16(kf, qf[km], a0, 0, 0, 0);
        }
        __builtin_amdgcn_s_setprio(0);

        // softmax numerators + bf16 pack
        const int kbase = kt * 64 + wk * 32;
        unsigned W[8], PW[8];
#pragma unroll
        for (int i = 0; i < 8; ++i) {
            const int r0 = 2 * i;
            const int kl0 = (r0 & 3) + 8 * (r0 >> 2) + 4 * hi;
            const float p0 = (kbase + kl0 > qrow) ? 0.f : __expf((a0[r0] + a1[r0]) * scale);
            const float p1 = (kbase + kl0 + 1 > qrow) ? 0.f : __expf((a0[r0 + 1] + a1[r0 + 1]) * scale);
            W[i] = (unsigned)f2bf(p0) | ((unsigned)f2bf(p1) << 16);
        }
#pragma unroll
        for (int i = 0; i < 8; ++i)
            PW[i] = (unsigned)__shfl_xor((int)W[i], 32, 64);

        // PV A-frags
        bf16x8 pa[2];
        u32x4 frs[2];
#pragma unroll
        for (int kc = 0; kc < 2; ++kc) {
            u32x4 fr;
            fr[0] = hi ? PW[kc * 4 + 2] : W[kc * 4 + 0];
            fr[1] = hi ? PW[kc * 4 + 3] : W[kc * 4 + 1];
            fr[2] = hi ? W[kc * 4 + 2] : PW[kc * 4 + 0];
            fr[3] = hi ? W[kc * 4 + 3] : PW[kc * 4 + 1];
            frs[kc] = fr;
            pa[kc] = __builtin_bit_cast(bf16x8, fr);
        }

        // PV first (matrix pipe), attn stores issue under it
        __builtin_amdgcn_s_setprio(1);
#pragma unroll
        for (int dt = 0; dt < 4; ++dt) {
            const int d = dt * 32 + l31;
            const int rowb = d * 128;
            const int sw = (d & 7) << 4;
#pragma unroll
            for (int kc = 0; kc < 2; ++kc) {
                const int jc = wk * 4 + kc * 2 + hi;
                bf16x8 vf = *(const bf16x8*)(vbuf + rowb + ((jc << 4) ^ sw));
                oacc[dt] = __builtin_amdgcn_mfma_f32_32x32x16_bf16(pa[kc], vf, oacc[dt], 0, 0, 0);
            }
        }
        __builtin_amdgcn_s_setprio(0);

        // normalized attn store from saved fr words
        float* arow = attn_row + kbase;
#pragma unroll
        for (int kc = 0; kc < 2; ++kc) {
            const u32x4 fr = frs[kc];
            f32x4 s0, s1;
            s0[0] = __builtin_bit_cast(float, fr[0] << 16) * invl_l;
            s0[1] = __builtin_bit_cast(float, fr[0] & 0xffff0000u) * invl_l;
            s0[2] = __builtin_bit_cast(float, fr[1] << 16) * invl_l;
            s0[3] = __builtin_bit_cast(float, fr[1] & 0xffff0000u) * invl_l;
            s1[0] = __builtin_bit_cast(float, fr[2] << 16) * invl_l;
            s1[1] = __builtin_bit_cast(float, fr[2] & 0xffff0000u) * invl_l;
            s1[2] = __builtin_bit_cast(float, fr[3] << 16) * invl_l;
            s1[3] = __builtin_bit_cast(float, fr[3] & 0xffff0000u) * invl_l;
            *(f32x4*)(arow + kc * 16 + hi * 8) = s0;
            *(f32x4*)(arow + kc * 16 + hi * 8 + 4) = s1;
        }
        __builtin_amdgcn_sched_barrier(0);
        __builtin_amdgcn_s_barrier();
        buf ^= 1;
    }

    // epilogue: reduce wk halves' partial O through LDS, normalize, store
    __syncthreads();
    float* red = (float*)lds;
    if (wk) {
#pragma unroll
        for (int dt = 0; dt < 4; ++dt)
#pragma unroll
            for (int r = 0; r < 16; ++r) {
                const int qr = (r & 3) + 8 * (r >> 2) + 4 * hi;
                red[wq * 4096 + qr * 128 + dt * 32 + l31] = oacc[dt][r];
            }
    }
    __syncthreads();
    if (!wk) {
        float iv[16];
#pragma unroll
        for (int r = 0; r < 16; ++r) {
            const int qr = (r & 3) + 8 * (r >> 2) + 4 * hi;
            iv[r] = __shfl(invl_l, qr, 64);
        }
        float* ob = outg + ((long)b * S_ + q0 + wq * 32) * D_;
#pragma unroll
        for (int dt = 0; dt < 4; ++dt)
#pragma unroll
            for (int r = 0; r < 16; ++r) {
                const int qr = (r & 3) + 8 * (r >> 2) + 4 * hi;
                ob[(long)qr * D_ + dt * 32 + l31] =
                    (oacc[dt][r] + red[wq * 4096 + qr * 128 + dt * 32 + l31]) * iv[r];
            }
    }

    // balanced zero-fill of this q-tile's masked region (wk==1 waves start immediately)
    {
        const int col0 = nt * 64;
        if (col0 < S_) {
            const int nch = (S_ - col0) >> 2;
            const f32x4 z = {0.f, 0.f, 0.f, 0.f};
            float* fb = attng + ((long)b * S_ + q0) * S_ + col0;
            for (int row = w; row < 64; row += 4) {
                float* rb = fb + (long)row * S_;
                for (int c = lane; c < nch; c += 64)
                    *(f32x4*)(rb + c * 4) = z;
            }
        }
    }
}

// ---------------- tiny-ws fallback (validated round-2 kernel) ----------------
__global__ __launch_bounds__(256, 2)
void attn_fallback(const float* __restrict__ qg, const float* __restrict__ kg,
                   const float* __restrict__ vg,
                   float* __restrict__ outg, float* __restrict__ attng)
{
    __shared__ unsigned short kT[64 * 128];
    __shared__ unsigned short vT[128 * 64];
    __shared__ unsigned short pT[4][16 * 64];
    const int tid = threadIdx.x, lane = tid & 63, w = tid >> 6;
    const int l15 = lane & 15, l4 = lane >> 4;
    const int bid = blockIdx.x;
    const int b = bid >> 5, qt = 31 - (bid & 31), q0 = qt * 64;
    const float scale = 0.088388347648318447f;
    bf16x8 qf[4];
    {
        const float* qrow = qg + ((long)b * S_ + q0 + w * 16 + l15) * D_;
#pragma unroll
        for (int kk = 0; kk < 4; ++kk) {
            const int d0 = kk * 32 + l4 * 8;
            f32x4 a = *(const f32x4*)(qrow + d0);
            f32x4 c = *(const f32x4*)(qrow + d0 + 4);
            bf16x8 t;
            t[0] = (short)f2bf(a[0]); t[1] = (short)f2bf(a[1]);
            t[2] = (short)f2bf(a[2]); t[3] = (short)f2bf(a[3]);
            t[4] = (short)f2bf(c[0]); t[5] = (short)f2bf(c[1]);
            t[6] = (short)f2bf(c[2]); t[7] = (short)f2bf(c[3]);
            qf[kk] = t;
        }
    }
    float m[4], l[4];
#pragma unroll
    for (int r = 0; r < 4; ++r) { m[r] = -1e30f; l[r] = 0.f; }
    for (int kt = 0; kt <= qt; ++kt) {
        __syncthreads();
        {
            const float* kbase = kg + ((long)b * S_ + kt * 64) * D_;
#pragma unroll
            for (int it = 0; it < 8; ++it) {
                const int c = tid + it * 256, row = c >> 5, dc = c & 31;
                f32x4 a = *(const f32x4*)(kbase + row * D_ + dc * 4);
                u32x2 p;
                p[0] = (unsigned)f2bf(a[0]) | ((unsigned)f2bf(a[1]) << 16);
                p[1] = (unsigned)f2bf(a[2]) | ((unsigned)f2bf(a[3]) << 16);
                *(u32x2*)((char*)kT + row * 256 + ((dc * 8) ^ ((row & 7) << 4))) = p;
            }
        }
        __syncthreads();
        f32x4 acc[4];
#pragma unroll
        for (int n = 0; n < 4; ++n) {
            f32x4 a = {0.f, 0.f, 0.f, 0.f};
            const int krow = n * 16 + l15, rb = krow * 256, swz = (krow & 7) << 4;
#pragma unroll
            for (int kk = 0; kk < 4; ++kk) {
                bf16x8 bf = *(const bf16x8*)((const char*)kT + rb + ((l4 * 16 + kk * 64) ^ swz));
                a = __builtin_amdgcn_mfma_f32_16x16x32_bf16(qf[kk], bf, a, 0, 0, 0);
            }
            acc[n] = a;
        }
        const bool diag = (kt == qt);
        float tm[4] = {-3e38f, -3e38f, -3e38f, -3e38f};
#pragma unroll
        for (int n = 0; n < 4; ++n)
#pragma unroll
            for (int r = 0; r < 4; ++r) {
                float s = acc[n][r] * scale;
                if (diag && (n * 16 + l15 > w * 16 + l4 * 4 + r)) s = -3e38f;
                acc[n][r] = s; tm[r] = fmaxf(tm[r], s);
            }
#pragma unroll
        for (int off = 1; off < 16; off <<= 1)
#pragma unroll
            for (int r = 0; r < 4; ++r) tm[r] = fmaxf(tm[r], __shfl_xor(tm[r], off, 64));
        float sum[4], mn[4];
#pragma unroll
        for (int r = 0; r < 4; ++r) {
            mn[r] = fmaxf(m[r], tm[r]);
            float s0 = 0.f;
#pragma unroll
            for (int n = 0; n < 4; ++n) s0 += __expf(acc[n][r] - mn[r]);
            sum[r] = s0;
        }
#pragma unroll
        for (int off = 1; off < 16; off <<= 1)
#pragma unroll
            for (int r = 0; r < 4; ++r) sum[r] += __shfl_xor(sum[r], off, 64);
#pragma unroll
        for (int r = 0; r < 4; ++r) { l[r] = l[r] * __expf(m[r] - mn[r]) + sum[r]; m[r] = mn[r]; }
    }
    float invl[4];
#pragma unroll
    for (int r = 0; r < 4; ++r) invl[r] = 1.f / l[r];
    f32x4 oacc[8];
#pragma unroll
    for (int n = 0; n < 8; ++n) oacc[n] = (f32x4){0.f, 0.f, 0.f, 0.f};
    float* attn_base = attng + ((long)b * S_ + q0) * S_;
    for (int kt = 0; kt <= qt; ++kt) {
        __syncthreads();
        {
            const float* kbase = kg + ((long)b * S_ + kt * 64) * D_;
#pragma unroll
            for (int it = 0; it < 8; ++it) {
                const int c = tid + it * 256, row = c >> 5, dc = c & 31;
                f32x4 a = *(const f32x4*)(kbase + row * D_ + dc * 4);
                u32x2 p;
                p[0] = (unsigned)f2bf(a[0]) | ((unsigned)f2bf(a[1]) << 16);
                p[1] = (unsigned)f2bf(a[2]) | ((unsigned)f2bf(a[3]) << 16);
                *(u32x2*)((char*)kT + row * 256 + ((dc * 8) ^ ((row & 7) << 4))) = p;
            }
        }
        {
            const float* vbase = vg + ((long)b * S_ + kt * 64) * D_;
#pragma unroll
            for (int it = 0; it < 8; ++it) {
                const int c = tid + it * 256, kr = c & 63, dq = c >> 6;
                f32x4 a = *(const f32x4*)(vbase + kr * D_ + dq * 4);
#pragma unroll
                for (int j = 0; j < 4; ++j) {
                    const int d = dq * 4 + j;
                    *(unsigned short*)((char*)vT + d * 128 + ((kr * 2) ^ ((d & 7) << 4))) = f2bf(a[j]);
                }
            }
        }
        __syncthreads();
        f32x4 acc[4];
#pragma unroll
        for (int n = 0; n < 4; ++n) {
            f32x4 a = {0.f, 0.f, 0.f, 0.f};
            const int krow = n * 16 + l15, rb = krow * 256, swz = (krow & 7) << 4;
#pragma unroll
            for (int kk = 0; kk < 4; ++kk) {
                bf16x8 bf = *(const bf16x8*)((const char*)kT + rb + ((l4 * 16 + kk * 64) ^ swz));
                a = __builtin_amdgcn_mfma_f32_16x16x32_bf16(qf[kk], bf, a, 0, 0, 0);
            }
            acc[n] = a;
        }
        const bool diag = (kt == qt);
#pragma unroll
        for (int n = 0; n < 4; ++n)
#pragma unroll
            for (int r = 0; r < 4; ++r) {
                float s = acc[n][r] * scale;
                if (diag && (n * 16 + l15 > w * 16 + l4 * 4 + r)) s = -3e38f;
                const float p = __expf(s - m[r]) * invl[r];
                attn_base[(long)(w * 16 + l4 * 4 + r) * S_ + kt * 64 + n * 16 + l15] = p;
                const int prow = l4 * 4 + r;
                *(unsigned short*)((char*)&pT[w][0] + prow * 128 + ((n * 32 + l15 * 2) ^ ((prow & 7) << 4))) = f2bf(p);
            }
        asm volatile("s_waitcnt lgkmcnt(0)" ::: "memory");
        __builtin_amdgcn_sched_barrier(0);
        bf16x8 pa[2];
#pragma unroll
        for (int kk = 0; kk < 2; ++kk)
            pa[kk] = *(const bf16x8*)((const char*)&pT[w][0] + l15 * 128 + ((l4 * 16 + kk * 64) ^ ((l15 & 7) << 4)));
#pragma unroll
        for (int n = 0; n < 8; ++n) {
            const int vrow = n * 16 + l15, rb = vrow * 128, swz = (vrow & 7) << 4;
#pragma unroll
            for (int kk = 0; kk < 2; ++kk) {
                bf16x8 bv = *(const bf16x8*)((const char*)vT + rb + ((l4 * 16 + kk * 64) ^ swz));
                oacc[n] = __builtin_amdgcn_mfma_f32_16x16x32_bf16(pa[kk], bv, oacc[n], 0, 0, 0);
            }
        }
    }
    {
        float* obase = outg + ((long)b * S_ + q0 + w * 16) * D_;
#pragma unroll
        for (int n = 0; n < 8; ++n)
#pragma unroll
            for (int r = 0; r < 4; ++r)
                obase[(long)(l4 * 4 + r) * D_ + n * 16 + l15] = oacc[n][r];
    }
    {
        const int col0 = (qt + 1) * 64;
        if (col0 < S_) {
            const int nch = (S_ - col0) >> 2;
            const f32x4 z = {0.f, 0.f, 0.f, 0.f};
            for (int row = w; row < 64; row += 4) {
                float* rbase = attn_base + (long)row * S_ + col0;
                for (int c = lane; c < nch; c += 64)
                    *(f32x4*)(rbase + c * 4) = z;
            }
        }
    }
}

extern "C" void kernel_launch(void* const* d_in, const int* in_sizes, int n_in,
                              void* d_out, int out_size, void* d_ws, size_t ws_size,
                              hipStream_t stream) {
    const float* q = (const float*)d_in[0];
    const float* k = (const float*)d_in[1];
    const float* v = (const float*)d_in[2];
    float* out  = (float*)d_out;
    float* attn = out + (long)B_ * S_ * D_;
    const size_t NEED = 2u * 8388608u;   // kws + vws = 16.8 MB
    if (ws_size >= NEED) {
        char* kws = (char*)d_ws;
        char* vws = kws + 8388608;
        conv_kv<<<dim3(1024), dim3(256), 0, stream>>>(k, v, kws, vws);
        flash_fused<<<dim3(512), dim3(256), 0, stream>>>(q, kws, vws, out, attn);
    } else {
        attn_fallback<<<dim3(512), dim3(256), 0, stream>>>(q, k, v, out, attn);
    }
}